// Round 9
// baseline (8329.247 us; speedup 1.0000x reference)
//
#include <hip/hip_runtime.h>

// dims: B=4 N=2048 E=1600 R=448 H=512 P=2 NH=4 DH=128 FF=2048
// Inputs: float32 (+int32). Everything f32 end-to-end. OUTPUT IS FLOAT32.

// ---------- C[8192,N] = act(A[8192,K] @ W[K,N] + bias) ----------
template <int MODE>  // 0 +bias; 1 +bias,PReLU; 2 +bias,+res
__global__ __launch_bounds__(256) void k_proj(
    const float* __restrict__ A, const float* __restrict__ W,
    const float* __restrict__ bias, const float* __restrict__ alpha,
    const float* __restrict__ res, float* __restrict__ C, int K, int N) {
  const int tid = threadIdx.x;
  const int m0 = blockIdx.x * 64 + (tid >> 4) * 4;
  const int n0 = blockIdx.y * 64 + (tid & 15) * 4;
  float acc[4][4] = {};
  for (int kk = 0; kk < K; kk++) {
    float a[4], wv[4];
#pragma unroll
    for (int i = 0; i < 4; i++) a[i] = A[(long)(m0 + i) * K + kk];
#pragma unroll
    for (int j = 0; j < 4; j++) wv[j] = W[(long)kk * N + n0 + j];
#pragma unroll
    for (int i = 0; i < 4; i++)
#pragma unroll
      for (int j = 0; j < 4; j++) acc[i][j] += a[i] * wv[j];
  }
#pragma unroll
  for (int i = 0; i < 4; i++) {
    const int m = m0 + i;
#pragma unroll
    for (int j = 0; j < 4; j++) {
      const int n = n0 + j;
      float vv = acc[i][j] + bias[n];
      if (MODE == 1) { if (vv < 0.f) vv *= alpha[n]; }
      if (MODE == 2) vv += res[(long)m * N + n];
      C[(long)m * N + n] = vv;
    }
  }
}

// ---------- S[zloc,qi,ki] = adjs[b,qi,ki] ? (q.k)/sqrt(128) : -1e9 ----------
__global__ __launch_bounds__(256) void k_scores(
    const float* __restrict__ q, const float* __restrict__ k,
    const int* __restrict__ adjs, float* __restrict__ Sc, int z0) {
  const int z = z0 + blockIdx.z;
  const int b = z >> 2, h = z & 3;
  const int tid = threadIdx.x;
  const int qi0 = blockIdx.x * 64 + (tid >> 4) * 4;
  const int ki0 = blockIdx.y * 64 + (tid & 15) * 4;
  const float* qb = q + (long)b * 2048 * 512 + h * 128;
  const float* kb = k + (long)b * 2048 * 512 + h * 128;
  float acc[4][4] = {};
  for (int d = 0; d < 128; d++) {
    float qa[4], ka[4];
#pragma unroll
    for (int i = 0; i < 4; i++) qa[i] = qb[(long)(qi0 + i) * 512 + d];
#pragma unroll
    for (int j = 0; j < 4; j++) ka[j] = kb[(long)(ki0 + j) * 512 + d];
#pragma unroll
    for (int i = 0; i < 4; i++)
#pragma unroll
      for (int j = 0; j < 4; j++) acc[i][j] += qa[i] * ka[j];
  }
  const float scale = 0.08838834764831845f;
#pragma unroll
  for (int i = 0; i < 4; i++) {
    const int qi = qi0 + i;
    const int* arow = adjs + ((long)b * 2048 + qi) * 2048;
    float* srow = Sc + ((long)blockIdx.z * 2048 + qi) * 2048;
#pragma unroll
    for (int j = 0; j < 4; j++) {
      const int ki = ki0 + j;
      srow[ki] = arow[ki] ? acc[i][j] * scale : -1.0e9f;
    }
  }
}

// ---------- o[b,qi,h,d] = sum_ki P[zloc,qi,ki] * v[b,ki,h,d] ----------
__global__ __launch_bounds__(256) void k_pv(
    const float* __restrict__ P, const float* __restrict__ v,
    float* __restrict__ o, int z0) {
  const int z = z0 + blockIdx.z;
  const int b = z >> 2, h = z & 3;
  const int tid = threadIdx.x;
  const int qi0 = blockIdx.x * 64 + (tid >> 4) * 4;
  const int d0 = blockIdx.y * 64 + (tid & 15) * 4;
  const float* Pb = P + (long)blockIdx.z * 2048 * 2048;
  const float* vb = v + (long)b * 2048 * 512 + h * 128;
  float acc[4][4] = {};
  for (int ki = 0; ki < 2048; ki++) {
    float pa[4], va[4];
#pragma unroll
    for (int i = 0; i < 4; i++) pa[i] = Pb[(long)(qi0 + i) * 2048 + ki];
#pragma unroll
    for (int j = 0; j < 4; j++) va[j] = vb[(long)ki * 512 + d0 + j];
#pragma unroll
    for (int i = 0; i < 4; i++)
#pragma unroll
      for (int j = 0; j < 4; j++) acc[i][j] += pa[i] * va[j];
  }
#pragma unroll
  for (int i = 0; i < 4; i++)
#pragma unroll
    for (int j = 0; j < 4; j++)
      o[((long)b * 2048 + qi0 + i) * 512 + h * 128 + d0 + j] = acc[i][j];
}

// ---------- LayerNorm rows of 512 ----------
__global__ __launch_bounds__(256) void k_ln(const float* __restrict__ in, float* __restrict__ out,
                                            const float* __restrict__ g, const float* __restrict__ bb) {
  __shared__ float rs[256], rq[256];
  const int row = blockIdx.x, tid = threadIdx.x;
  const float* p = in + (long)row * 512;
  const float a0 = p[tid], a1 = p[tid + 256];
  rs[tid] = a0 + a1;
  rq[tid] = a0 * a0 + a1 * a1;
  __syncthreads();
  for (int s = 128; s > 0; s >>= 1) {
    if (tid < s) { rs[tid] += rs[tid + s]; rq[tid] += rq[tid + s]; }
    __syncthreads();
  }
  const float mu = rs[0] * (1.f / 512.f);
  const float var = rq[0] * (1.f / 512.f) - mu * mu;
  const float inv = 1.0f / sqrtf(var + 1e-5f);
  float* po = out + (long)row * 512;
  po[tid] = (a0 - mu) * inv * g[tid] + bb[tid];
  po[tid + 256] = (a1 - mu) * inv * g[tid + 256] + bb[tid + 256];
}

// ---------- softmax rows of 2048 (in place) ----------
__global__ __launch_bounds__(256) void k_softmax(float* __restrict__ S) {
  __shared__ float red[256];
  const int tid = threadIdx.x;
  float* p = S + (long)blockIdx.x * 2048;
  float v[8];
  float m = -3.4e38f;
#pragma unroll
  for (int i = 0; i < 8; i++) { v[i] = p[i * 256 + tid]; m = fmaxf(m, v[i]); }
  red[tid] = m;
  __syncthreads();
  for (int s = 128; s > 0; s >>= 1) {
    if (tid < s) red[tid] = fmaxf(red[tid], red[tid + s]);
    __syncthreads();
  }
  m = red[0];
  __syncthreads();
  float sum = 0.f;
#pragma unroll
  for (int i = 0; i < 8; i++) { v[i] = expf(v[i] - m); sum += v[i]; }
  red[tid] = sum;
  __syncthreads();
  for (int s = 128; s > 0; s >>= 1) {
    if (tid < s) red[tid] += red[tid + s];
    __syncthreads();
  }
  const float inv = 1.f / red[0];
#pragma unroll
  for (int i = 0; i < 8; i++) p[i * 256 + tid] = v[i] * inv;
}

// ---------- x = concat(vents, renc_w[rels], axis=1) ----------
__global__ __launch_bounds__(256) void k_build_x(const float* __restrict__ vents,
                                                 const int* __restrict__ rels,
                                                 const float* __restrict__ renc,
                                                 float* __restrict__ x) {
  const long idx = (long)blockIdx.x * 256 + threadIdx.x;  // < 8192*512
  const int c = (int)(idx & 511);
  const int row = (int)(idx >> 9);
  const int b = row >> 11, n = row & 2047;
  float val;
  if (n < 1600) val = vents[((long)b * 1600 + n) * 512 + c];
  else val = renc[(long)rels[b * 448 + (n - 1600)] * 512 + c];
  x[idx] = val;
}

// ---------- out(f32) = concat(glob(4,512), gents(4,2048,512), emask(4,2048)) ----------
__global__ __launch_bounds__(256) void k_out(const float* __restrict__ x, const int* __restrict__ entlen,
                                             float* __restrict__ out, long out_n) {
  const long idx = (long)blockIdx.x * 256 + threadIdx.x;
  if (idx >= out_n) return;
  const long G = 2048, GE = 2048 + 4194304;
  float v;
  if (idx < G) {
    const int b = (int)(idx >> 9), c = (int)(idx & 511);
    int e = entlen[0];
    if (e < 0 || e >= 2048) e = 1600;
    v = x[((long)b * 2048 + e) * 512 + c];
  } else if (idx < GE) {
    v = x[idx - G];
  } else {
    v = 1.0f;
  }
  out[idx] = v;
}

extern "C" void kernel_launch(void* const* d_in, const int* in_sizes, int n_in,
                              void* d_out, int out_size, void* d_ws, size_t ws_size,
                              hipStream_t stream) {
  const int* adjs = (const int*)d_in[0];
  const int* rels = (const int*)d_in[1];
  const float* vents = (const float*)d_in[2];
  const int* entlen = (const int*)d_in[3];
  const float* renc = (const float*)d_in[4];
  const float* Wq = (const float*)d_in[5];
  const float* Wk = (const float*)d_in[6];
  const float* Wv = (const float*)d_in[7];
  const float* Wo = (const float*)d_in[8];
  const float* W1 = (const float*)d_in[9];
  const float* W2 = (const float*)d_in[10];
  const float* bq = (const float*)d_in[11];
  const float* bk = (const float*)d_in[12];
  const float* bv = (const float*)d_in[13];
  const float* bo = (const float*)d_in[14];
  const float* b1 = (const float*)d_in[15];
  const float* b2 = (const float*)d_in[16];
  const float* ln1g = (const float*)d_in[17];
  const float* ln1b = (const float*)d_in[18];
  const float* ln2g = (const float*)d_in[19];
  const float* ln2b = (const float*)d_in[20];
  const float* prelu = (const float*)d_in[21];

  // f32 workspace: x@0 t@1 o@2 q@3 k@4 v@5 spare@6 (hb overlays 3..6), S@7
  const long SZ = 4194304;  // 8192*512 == 2048*2048
  float* Wp = (float*)d_ws;
  float* x = Wp;
  float* t = Wp + SZ;
  float* o = Wp + 2 * SZ;
  float* q = Wp + 3 * SZ;
  float* k = Wp + 4 * SZ;
  float* v = Wp + 5 * SZ;
  float* hb = Wp + 3 * SZ;  // 4*SZ overlay on q,k,v,spare (dead during FFN)
  float* S = Wp + 7 * SZ;

  long avail = (long)(ws_size / 4) - 7 * SZ;
  long cap = avail / SZ;
  int nz = cap >= 16 ? 16 : (cap < 1 ? 1 : (int)cap);

  k_build_x<<<dim3(16384), 256, 0, stream>>>(vents, rels, renc, x);

  for (int j = 0; j < 2; j++) {
    const float* wq = Wq + (long)j * 262144;
    const float* wk = Wk + (long)j * 262144;
    const float* wv = Wv + (long)j * 262144;
    const float* wo = Wo + (long)j * 262144;
    const float* w1 = W1 + (long)j * 1048576;
    const float* w2 = W2 + (long)j * 1048576;

    k_proj<0><<<dim3(128, 8), 256, 0, stream>>>(x, wq, bq + j * 512, nullptr, nullptr, q, 512, 512);
    k_proj<0><<<dim3(128, 8), 256, 0, stream>>>(x, wk, bk + j * 512, nullptr, nullptr, k, 512, 512);
    k_proj<0><<<dim3(128, 8), 256, 0, stream>>>(x, wv, bv + j * 512, nullptr, nullptr, v, 512, 512);

    for (int z0 = 0; z0 < 16; z0 += nz) {
      const int nzc = (16 - z0) < nz ? (16 - z0) : nz;
      k_scores<<<dim3(32, 32, nzc), 256, 0, stream>>>(q, k, adjs, S, z0);
      k_softmax<<<dim3(nzc * 2048), 256, 0, stream>>>(S);
      k_pv<<<dim3(32, 2, nzc), 256, 0, stream>>>(S, v, o, z0);
    }

    // attn_out = o @ Wo + bo -> x (x dead until LN2 rewrites it)
    k_proj<0><<<dim3(128, 8), 256, 0, stream>>>(o, wo, bo + j * 512, nullptr, nullptr, x, 512, 512);
    // t = LN1(attn_out)
    k_ln<<<dim3(8192), 256, 0, stream>>>(x, t, ln1g + j * 512, ln1b + j * 512);
    // hb = PReLU(t @ W1 + b1)
    k_proj<1><<<dim3(128, 32), 256, 0, stream>>>(t, w1, b1 + j * 2048, prelu + j * 2048, nullptr, hb, 512, 2048);
    // o = hb @ W2 + b2 + t
    k_proj<2><<<dim3(128, 8), 256, 0, stream>>>(hb, w2, b2 + j * 512, nullptr, t, o, 2048, 512);
    // x = LN2(o)
    k_ln<<<dim3(8192), 256, 0, stream>>>(o, x, ln2g + j * 512, ln2b + j * 512);
  }

  const long out_n = (long)out_size;
  k_out<<<dim3((unsigned)((out_n + 255) / 256)), 256, 0, stream>>>(x, entlen, (float*)d_out, out_n);
}

// Round 10
// 1181.335 us; speedup vs baseline: 7.0507x; 7.0507x over previous
//
#include <hip/hip_runtime.h>

typedef unsigned short u16;
typedef __bf16 bf16x8 __attribute__((ext_vector_type(8)));
typedef float floatx4 __attribute__((ext_vector_type(4)));

// dims: B=4 N=2048 E=1600 R=448 H=512 P=2 NH=4 DH=128 FF=2048
// f32 inputs/outputs; bf16 MFMA GEMMs with f32 accumulate; f32 master path
// for softmax/LN/residual. GEMM core + transposes: r4-validated structure.

__device__ __forceinline__ float bf2f(u16 u) {
  union { unsigned int i; float f; } c; c.i = ((unsigned int)u) << 16; return c.f;
}
__device__ __forceinline__ u16 f2bf(float f) {
  union { unsigned int i; float f; } c; c.f = f;
  unsigned int i = c.i;
  return (u16)((i + 0x7FFFu + ((i >> 16) & 1u)) >> 16);
}

// ---------------- bf16 TN GEMM: C[m,n] = sum_k A[m,k]*Bt[n,k] ----------------
// EPI: 0 none, 1 +bias, 2 +bias+PReLU, 3 +bias+res(f32), 4 mask*scale
// FOUT: 1 -> C float, 0 -> C bf16
template <int EPI, int FOUT>
__global__ __launch_bounds__(256, 2) void gemm_tn(
    const u16* __restrict__ A, const u16* __restrict__ Bt, void* __restrict__ Cv,
    const float* __restrict__ bias, const float* __restrict__ alpha,
    const float* __restrict__ res, const int* __restrict__ mask,
    int K, int lda, int ldb, int ldc, int z0, int zdiv,
    long a_out, long a_in, long b_out, long b_in, long c_out, long c_in, long m_out,
    float scale) {
  __shared__ __align__(16) u16 As[128 * 32];
  __shared__ __align__(16) u16 Bs[128 * 32];

  const int tid = threadIdx.x;
  const int w = tid >> 6, lane = tid & 63;
  const int quad = lane >> 4, l16 = lane & 15;
  const int wm = w & 1, wn = w >> 1;
  const int z = blockIdx.z + z0;
  const int zq = z / zdiv, zr = z % zdiv;

  const long aoff = (long)zq * a_out + (long)zr * a_in;
  const long boff = (long)zq * b_out + (long)zr * b_in;
  const long coff = (long)zq * c_out + (long)zr * c_in;

  const int slot0 = w * 128 + lane;
  const int slot1 = slot0 + 64;
  const u16* pA0 = A + aoff + (long)(blockIdx.x * 128 + (slot0 >> 2)) * lda + (slot0 & 3) * 8;
  const u16* pA1 = A + aoff + (long)(blockIdx.x * 128 + (slot1 >> 2)) * lda + (slot1 & 3) * 8;
  const u16* pB0 = Bt + boff + (long)(blockIdx.y * 128 + (slot0 >> 2)) * ldb + (slot0 & 3) * 8;
  const u16* pB1 = Bt + boff + (long)(blockIdx.y * 128 + (slot1 >> 2)) * ldb + (slot1 & 3) * 8;

  const floatx4 z4 = {0.f, 0.f, 0.f, 0.f};
  floatx4 acc[4][4];
#pragma unroll
  for (int i = 0; i < 4; i++)
#pragma unroll
    for (int j = 0; j < 4; j++) acc[i][j] = z4;

  for (int k0 = 0; k0 < K; k0 += 32) {
    int4 a0 = *(const int4*)pA0;
    int4 a1 = *(const int4*)pA1;
    int4 b0 = *(const int4*)pB0;
    int4 b1 = *(const int4*)pB1;
    pA0 += 32; pA1 += 32; pB0 += 32; pB1 += 32;
    __syncthreads();
    *(int4*)&As[slot0 * 8] = a0;
    *(int4*)&As[slot1 * 8] = a1;
    *(int4*)&Bs[slot0 * 8] = b0;
    *(int4*)&Bs[slot1 * 8] = b1;
    __syncthreads();

    bf16x8 af[4], bv[4];
#pragma unroll
    for (int mi = 0; mi < 4; mi++)
      af[mi] = *(const bf16x8*)&As[(wm * 64 + mi * 16 + l16) * 32 + quad * 8];
#pragma unroll
    for (int ni = 0; ni < 4; ni++)
      bv[ni] = *(const bf16x8*)&Bs[(wn * 64 + ni * 16 + l16) * 32 + quad * 8];
#pragma unroll
    for (int mi = 0; mi < 4; mi++)
#pragma unroll
      for (int ni = 0; ni < 4; ni++)
        acc[mi][ni] = __builtin_amdgcn_mfma_f32_16x16x32_bf16(af[mi], bv[ni], acc[mi][ni], 0, 0, 0);
  }

  const long crow0 = (long)blockIdx.x * 128;
  const int ncol0 = blockIdx.y * 128 + wn * 64 + l16;
#pragma unroll
  for (int mi = 0; mi < 4; mi++) {
#pragma unroll
    for (int r = 0; r < 4; r++) {
      const int m = wm * 64 + mi * 16 + quad * 4 + r;
      const long rowbase = coff + (crow0 + m) * (long)ldc;
      const int* mrow = (EPI == 4) ? (mask + (long)zq * m_out + (crow0 + m) * (long)ldc) : nullptr;
      const float* rrow = (EPI == 3) ? (res + rowbase) : nullptr;
#pragma unroll
      for (int ni = 0; ni < 4; ni++) {
        const int n = ncol0 + ni * 16;
        float vv = acc[mi][ni][r];
        if (EPI == 1 || EPI == 2 || EPI == 3) vv += bias[n];
        if (EPI == 2) { if (vv < 0.f) vv *= alpha[n]; }
        if (EPI == 3) vv += rrow[n];
        if (EPI == 4) vv = mrow[n] ? vv * scale : -1.0e9f;
        if (FOUT) ((float*)Cv)[rowbase + n] = vv;
        else ((u16*)Cv)[rowbase + n] = f2bf(vv);
      }
    }
  }
}

// ---------------- weight transpose + f32->bf16 (r4-validated) ----------------
__global__ __launch_bounds__(256) void tr_w(const float* __restrict__ src, u16* __restrict__ dst,
                                            int ld_src, int ld_dst, long s_z, long d_z) {
  __shared__ u16 tile[32][33];
  src += (long)blockIdx.z * s_z;
  dst += (long)blockIdx.z * d_z;
  const int r0 = blockIdx.x << 5, c0 = blockIdx.y << 5;
  const int tx = threadIdx.x & 31, ty = threadIdx.x >> 5;
#pragma unroll
  for (int i = 0; i < 32; i += 8)
    tile[ty + i][tx] = f2bf(src[(long)(r0 + ty + i) * ld_src + c0 + tx]);
  __syncthreads();
#pragma unroll
  for (int i = 0; i < 32; i += 8)
    dst[(long)(c0 + ty + i) * ld_dst + r0 + tx] = tile[tx][ty + i];
}

// ---------------- bf16 transpose for V (r4-validated) ----------------
__global__ __launch_bounds__(256) void tr_bf16(const u16* __restrict__ src, u16* __restrict__ dst,
                                               int ld_src, int ld_dst, int zdiv,
                                               long s_out, long s_in, long d_out, long d_in_) {
  __shared__ u16 tile[32][33];
  const int zz = blockIdx.z, zq = zz / zdiv, zr = zz % zdiv;
  src += (long)zq * s_out + (long)zr * s_in;
  dst += (long)zq * d_out + (long)zr * d_in_;
  const int r0 = blockIdx.x << 5, c0 = blockIdx.y << 5;
  const int tx = threadIdx.x & 31, ty = threadIdx.x >> 5;
#pragma unroll
  for (int i = 0; i < 32; i += 8) tile[ty + i][tx] = src[(long)(r0 + ty + i) * ld_src + c0 + tx];
  __syncthreads();
#pragma unroll
  for (int i = 0; i < 32; i += 8) dst[(long)(c0 + ty + i) * ld_dst + r0 + tx] = tile[tx][ty + i];
}

// ---------------- x = concat(vents, renc_w[rels]) -> f32 + bf16 ----------------
__global__ __launch_bounds__(256) void k_build_x(const float* __restrict__ vents,
                                                 const int* __restrict__ rels,
                                                 const float* __restrict__ renc,
                                                 float* __restrict__ x, u16* __restrict__ xb) {
  const long idx = (long)blockIdx.x * 256 + threadIdx.x;
  const int c = (int)(idx & 511);
  const int row = (int)(idx >> 9);
  const int b = row >> 11, n = row & 2047;
  float val;
  if (n < 1600) val = vents[((long)b * 1600 + n) * 512 + c];
  else val = renc[(long)rels[b * 448 + (n - 1600)] * 512 + c];
  x[idx] = val;
  xb[idx] = f2bf(val);
}

// ---------------- LayerNorm 512: f32 in -> f32 out + bf16 shadow ----------------
__global__ __launch_bounds__(256) void k_ln(const float* __restrict__ in, float* __restrict__ out,
                                            u16* __restrict__ outb,
                                            const float* __restrict__ g, const float* __restrict__ bb) {
  __shared__ float rs[256], rq[256];
  const int row = blockIdx.x, tid = threadIdx.x;
  const float* p = in + (long)row * 512;
  const float a0 = p[tid], a1 = p[tid + 256];
  rs[tid] = a0 + a1;
  rq[tid] = a0 * a0 + a1 * a1;
  __syncthreads();
  for (int s = 128; s > 0; s >>= 1) {
    if (tid < s) { rs[tid] += rs[tid + s]; rq[tid] += rq[tid + s]; }
    __syncthreads();
  }
  const float mu = rs[0] * (1.f / 512.f);
  const float var = rq[0] * (1.f / 512.f) - mu * mu;
  const float inv = 1.0f / sqrtf(var + 1e-5f);
  const float o0 = (a0 - mu) * inv * g[tid] + bb[tid];
  const float o1 = (a1 - mu) * inv * g[tid + 256] + bb[tid + 256];
  out[(long)row * 512 + tid] = o0;
  out[(long)row * 512 + tid + 256] = o1;
  outb[(long)row * 512 + tid] = f2bf(o0);
  outb[(long)row * 512 + tid + 256] = f2bf(o1);
}

// ---------------- softmax rows of 2048: f32 S -> bf16 P ----------------
__global__ __launch_bounds__(256) void k_softmax(const float* __restrict__ S, u16* __restrict__ P) {
  __shared__ float red[256];
  const int tid = threadIdx.x;
  const float* p = S + (long)blockIdx.x * 2048;
  u16* pb = P + (long)blockIdx.x * 2048;
  float v[8];
  float m = -3.4e38f;
#pragma unroll
  for (int i = 0; i < 8; i++) { v[i] = p[i * 256 + tid]; m = fmaxf(m, v[i]); }
  red[tid] = m;
  __syncthreads();
  for (int s = 128; s > 0; s >>= 1) {
    if (tid < s) red[tid] = fmaxf(red[tid], red[tid + s]);
    __syncthreads();
  }
  m = red[0];
  __syncthreads();
  float sum = 0.f;
#pragma unroll
  for (int i = 0; i < 8; i++) { v[i] = expf(v[i] - m); sum += v[i]; }
  red[tid] = sum;
  __syncthreads();
  for (int s = 128; s > 0; s >>= 1) {
    if (tid < s) red[tid] += red[tid + s];
    __syncthreads();
  }
  const float inv = 1.f / red[0];
#pragma unroll
  for (int i = 0; i < 8; i++) pb[i * 256 + tid] = f2bf(v[i] * inv);
}

// ---------------- out(f32) = concat(glob, gents, emask) ----------------
__global__ __launch_bounds__(256) void k_out(const float* __restrict__ x, const int* __restrict__ entlen,
                                             float* __restrict__ out, long out_n) {
  const long idx = (long)blockIdx.x * 256 + threadIdx.x;
  if (idx >= out_n) return;
  const long G = 2048, GE = 2048 + 4194304;
  float v;
  if (idx < G) {
    const int b = (int)(idx >> 9), c = (int)(idx & 511);
    int e = entlen[0];
    if (e < 0 || e >= 2048) e = 1600;
    v = x[((long)b * 2048 + e) * 512 + c];
  } else if (idx < GE) {
    v = x[idx - G];
  } else {
    v = 1.0f;
  }
  out[idx] = v;
}

extern "C" void kernel_launch(void* const* d_in, const int* in_sizes, int n_in,
                              void* d_out, int out_size, void* d_ws, size_t ws_size,
                              hipStream_t stream) {
  const int* adjs = (const int*)d_in[0];
  const int* rels = (const int*)d_in[1];
  const float* vents = (const float*)d_in[2];
  const int* entlen = (const int*)d_in[3];
  const float* renc = (const float*)d_in[4];
  const float* Wq = (const float*)d_in[5];
  const float* Wk = (const float*)d_in[6];
  const float* Wv = (const float*)d_in[7];
  const float* Wo = (const float*)d_in[8];
  const float* W1 = (const float*)d_in[9];
  const float* W2 = (const float*)d_in[10];
  const float* bq = (const float*)d_in[11];
  const float* bk = (const float*)d_in[12];
  const float* bv = (const float*)d_in[13];
  const float* bo = (const float*)d_in[14];
  const float* b1 = (const float*)d_in[15];
  const float* b2 = (const float*)d_in[16];
  const float* ln1g = (const float*)d_in[17];
  const float* ln1b = (const float*)d_in[18];
  const float* ln2g = (const float*)d_in[19];
  const float* ln2b = (const float*)d_in[20];
  const float* prelu = (const float*)d_in[21];

  const long SZ = 4194304;  // 8192*512 == 2048*2048 elements
  char* base = (char*)d_ws;
  // byte offsets
  float* x_f   = (float*)(base + 0);           // 16 MB
  float* t_f   = (float*)(base + 16777216);    // 16 MB
  float* tmp_f = (float*)(base + 33554432);    // 16 MB
  u16* wt  = (u16*)(base + 50331648);          // 12,582,912 B (2 layers x 3,145,728 elems)
  u16* xb  = (u16*)(base + 62914560);          // 8 MB each below
  u16* tb  = (u16*)(base + 71303168);
  u16* qb  = (u16*)(base + 79691776);
  u16* kb  = (u16*)(base + 88080384);
  u16* vb  = (u16*)(base + 96468992);
  u16* Vtb = (u16*)(base + 104857600);
  u16* ob  = (u16*)(base + 113246208);
  u16* hb  = (u16*)(base + 121634816);         // 32 MB
  const long fixed = 155189248;
  long avail = (long)ws_size - fixed;
  const long per_z = 25165824;  // 16 MB f32 S + 8 MB bf16 P
  long cap = avail / per_z;
  int nz = cap >= 16 ? 16 : (cap < 1 ? 1 : (int)cap);
  float* S = (float*)(base + fixed);                          // nz * 16 MB
  u16* Pb  = (u16*)(base + fixed + (long)nz * 16777216);      // nz * 8 MB

  k_build_x<<<dim3(16384), 256, 0, stream>>>(vents, rels, renc, x_f, xb);

  // weight transposes: per layer slot [wq wk wv wo | w1t | w2t]
  tr_w<<<dim3(16, 16, 2), 256, 0, stream>>>(Wq, wt + 0,       512, 512, 262144L, 3145728L);
  tr_w<<<dim3(16, 16, 2), 256, 0, stream>>>(Wk, wt + 262144,  512, 512, 262144L, 3145728L);
  tr_w<<<dim3(16, 16, 2), 256, 0, stream>>>(Wv, wt + 524288,  512, 512, 262144L, 3145728L);
  tr_w<<<dim3(16, 16, 2), 256, 0, stream>>>(Wo, wt + 786432,  512, 512, 262144L, 3145728L);
  tr_w<<<dim3(16, 64, 2), 256, 0, stream>>>(W1, wt + 1048576, 2048, 512, 1048576L, 3145728L);
  tr_w<<<dim3(64, 16, 2), 256, 0, stream>>>(W2, wt + 2097152, 512, 2048, 1048576L, 3145728L);

  const float scale = 0.08838834764831845f;

  for (int j = 0; j < 2; j++) {
    const u16* wqt = wt + (long)j * 3145728;
    const u16* wkt = wqt + 262144;
    const u16* wvt = wqt + 524288;
    const u16* wot = wqt + 786432;
    const u16* w1t = wqt + 1048576;
    const u16* w2t = wqt + 2097152;

    gemm_tn<1, 0><<<dim3(64, 4, 1), 256, 0, stream>>>(xb, wqt, qb, bq + j * 512, nullptr, nullptr, nullptr,
        512, 512, 512, 512, 0, 1, 0, 0, 0, 0, 0, 0, 0, 0.f);
    gemm_tn<1, 0><<<dim3(64, 4, 1), 256, 0, stream>>>(xb, wkt, kb, bk + j * 512, nullptr, nullptr, nullptr,
        512, 512, 512, 512, 0, 1, 0, 0, 0, 0, 0, 0, 0, 0.f);
    gemm_tn<1, 0><<<dim3(64, 4, 1), 256, 0, stream>>>(xb, wvt, vb, bv + j * 512, nullptr, nullptr, nullptr,
        512, 512, 512, 512, 0, 1, 0, 0, 0, 0, 0, 0, 0, 0.f);

    // Vtb[b,h,dh,kv] = vb[b,kv,h,dh]
    tr_bf16<<<dim3(64, 4, 16), 256, 0, stream>>>(vb, Vtb, 512, 2048, 4,
        1048576L, 128L, 1048576L, 262144L);

    for (int z0 = 0; z0 < 16; z0 += nz) {
      const int nzc = (16 - z0) < nz ? (16 - z0) : nz;
      // S(f32) = mask ? (q.k)*scale : -1e9
      gemm_tn<4, 1><<<dim3(16, 16, nzc), 256, 0, stream>>>(qb, kb, (void*)(S - (long)z0 * SZ),
          nullptr, nullptr, nullptr, adjs,
          128, 512, 512, 2048, z0, 4,
          1048576L, 128L, 1048576L, 128L, 16777216L, 4194304L, 4194304L, scale);
      k_softmax<<<dim3(nzc * 2048), 256, 0, stream>>>(S, Pb);
      // ob[b,q,h,dh] = P @ V
      gemm_tn<0, 0><<<dim3(16, 1, nzc), 256, 0, stream>>>(Pb - (long)z0 * SZ, Vtb, ob,
          nullptr, nullptr, nullptr, nullptr,
          2048, 2048, 2048, 512, z0, 4,
          16777216L, 4194304L, 1048576L, 262144L, 1048576L, 128L, 0, 0.f);
    }

    // attn_out(f32) = ob @ Wo + bo -> tmp
    gemm_tn<1, 1><<<dim3(64, 4, 1), 256, 0, stream>>>(ob, wot, tmp_f, bo + j * 512, nullptr, nullptr, nullptr,
        512, 512, 512, 512, 0, 1, 0, 0, 0, 0, 0, 0, 0, 0.f);
    // t = LN1(tmp) -> t_f + tb
    k_ln<<<dim3(8192), 256, 0, stream>>>(tmp_f, t_f, tb, ln1g + j * 512, ln1b + j * 512);
    // hb(bf16) = PReLU(t @ W1 + b1)
    gemm_tn<2, 0><<<dim3(64, 16, 1), 256, 0, stream>>>(tb, w1t, hb, b1 + j * 2048, prelu + j * 2048, nullptr, nullptr,
        512, 512, 512, 2048, 0, 1, 0, 0, 0, 0, 0, 0, 0, 0.f);
    // tmp(f32) = hb @ W2 + b2 + t_f
    gemm_tn<3, 1><<<dim3(64, 4, 1), 256, 0, stream>>>(hb, w2t, tmp_f, b2 + j * 512, nullptr, t_f, nullptr,
        2048, 2048, 2048, 512, 0, 1, 0, 0, 0, 0, 0, 0, 0, 0.f);
    // x = LN2(tmp) -> x_f + xb
    k_ln<<<dim3(8192), 256, 0, stream>>>(tmp_f, x_f, xb, ln2g + j * 512, ln2b + j * 512);
  }

  const long out_n = (long)out_size;
  k_out<<<dim3((unsigned)((out_n + 255) / 256)), 256, 0, stream>>>(x_f, entlen, (float*)d_out, out_n);
}

// Round 11
// 886.628 us; speedup vs baseline: 9.3943x; 1.3324x over previous
//
#include <hip/hip_runtime.h>

typedef unsigned short u16;
typedef __bf16 bf16x8 __attribute__((ext_vector_type(8)));
typedef float floatx4 __attribute__((ext_vector_type(4)));

// dims: B=4 N=2048 E=1600 R=448 H=512 P=2 NH=4 DH=128 FF=2048
// f32 in/out; bf16 MFMA GEMMs w/ f32 accum; flash-fused attention.

__device__ __forceinline__ float bf2f(u16 u) {
  union { unsigned int i; float f; } c; c.i = ((unsigned int)u) << 16; return c.f;
}
__device__ __forceinline__ u16 f2bf(float f) {
  union { unsigned int i; float f; } c; c.f = f;
  unsigned int i = c.i;
  return (u16)((i + 0x7FFFu + ((i >> 16) & 1u)) >> 16);
}

// ---------------- bf16 TN GEMM (r10-validated) ----------------
// EPI: 1 +bias, 2 +bias+PReLU, 3 +bias+res(f32). FOUT: 1 f32 out, 0 bf16 out.
template <int EPI, int FOUT>
__global__ __launch_bounds__(256, 2) void gemm_tn(
    const u16* __restrict__ A, const u16* __restrict__ Bt, void* __restrict__ Cv,
    const float* __restrict__ bias, const float* __restrict__ alpha,
    const float* __restrict__ res, int K, int lda, int ldb, int ldc) {
  __shared__ __align__(16) u16 As[128 * 32];
  __shared__ __align__(16) u16 Bs[128 * 32];

  const int tid = threadIdx.x;
  const int w = tid >> 6, lane = tid & 63;
  const int quad = lane >> 4, l16 = lane & 15;
  const int wm = w & 1, wn = w >> 1;

  const int slot0 = w * 128 + lane;
  const int slot1 = slot0 + 64;
  const u16* pA0 = A + (long)(blockIdx.x * 128 + (slot0 >> 2)) * lda + (slot0 & 3) * 8;
  const u16* pA1 = A + (long)(blockIdx.x * 128 + (slot1 >> 2)) * lda + (slot1 & 3) * 8;
  const u16* pB0 = Bt + (long)(blockIdx.y * 128 + (slot0 >> 2)) * ldb + (slot0 & 3) * 8;
  const u16* pB1 = Bt + (long)(blockIdx.y * 128 + (slot1 >> 2)) * ldb + (slot1 & 3) * 8;

  const floatx4 z4 = {0.f, 0.f, 0.f, 0.f};
  floatx4 acc[4][4];
#pragma unroll
  for (int i = 0; i < 4; i++)
#pragma unroll
    for (int j = 0; j < 4; j++) acc[i][j] = z4;

  for (int k0 = 0; k0 < K; k0 += 32) {
    int4 a0 = *(const int4*)pA0;
    int4 a1 = *(const int4*)pA1;
    int4 b0 = *(const int4*)pB0;
    int4 b1 = *(const int4*)pB1;
    pA0 += 32; pA1 += 32; pB0 += 32; pB1 += 32;
    __syncthreads();
    *(int4*)&As[slot0 * 8] = a0;
    *(int4*)&As[slot1 * 8] = a1;
    *(int4*)&Bs[slot0 * 8] = b0;
    *(int4*)&Bs[slot1 * 8] = b1;
    __syncthreads();

    bf16x8 af[4], bv[4];
#pragma unroll
    for (int mi = 0; mi < 4; mi++)
      af[mi] = *(const bf16x8*)&As[(wm * 64 + mi * 16 + l16) * 32 + quad * 8];
#pragma unroll
    for (int ni = 0; ni < 4; ni++)
      bv[ni] = *(const bf16x8*)&Bs[(wn * 64 + ni * 16 + l16) * 32 + quad * 8];
#pragma unroll
    for (int mi = 0; mi < 4; mi++)
#pragma unroll
      for (int ni = 0; ni < 4; ni++)
        acc[mi][ni] = __builtin_amdgcn_mfma_f32_16x16x32_bf16(af[mi], bv[ni], acc[mi][ni], 0, 0, 0);
  }

  const long crow0 = (long)blockIdx.x * 128;
  const int ncol0 = blockIdx.y * 128 + wn * 64 + l16;
#pragma unroll
  for (int mi = 0; mi < 4; mi++) {
#pragma unroll
    for (int r = 0; r < 4; r++) {
      const int m = wm * 64 + mi * 16 + quad * 4 + r;
      const long rowbase = (crow0 + m) * (long)ldc;
      const float* rrow = (EPI == 3) ? (res + rowbase) : nullptr;
#pragma unroll
      for (int ni = 0; ni < 4; ni++) {
        const int n = ncol0 + ni * 16;
        float vv = acc[mi][ni][r] + bias[n];
        if (EPI == 2) { if (vv < 0.f) vv *= alpha[n]; }
        if (EPI == 3) vv += rrow[n];
        if (FOUT) ((float*)Cv)[rowbase + n] = vv;
        else ((u16*)Cv)[rowbase + n] = f2bf(vv);
      }
    }
  }
}

// ---------------- flash-fused attention ----------------
// grid (16 qtiles, 16 bh). o[b,q,h,dh] = softmax(mask(QK^T/sqrt(128))) @ V
#define LDP 136
__global__ __launch_bounds__(256, 2) void k_attn(
    const u16* __restrict__ qg, const u16* __restrict__ kg,
    const u16* __restrict__ vt, const unsigned* __restrict__ mbits,
    u16* __restrict__ og) {
  __shared__ __align__(16) u16 KV[128 * LDP];
  __shared__ __align__(16) u16 Pl[128 * LDP];
  __shared__ unsigned Ml[128 * 4];

  const int tid = threadIdx.x;
  const int w = tid >> 6, lane = tid & 63;
  const int quad = lane >> 4, l16 = lane & 15;
  const int qt = blockIdx.x;
  const int z = blockIdx.y;
  const int b = z >> 2, h = z & 3;

  const u16* qbase = qg + (long)b * 2048 * 512 + h * 128;
  const u16* kbase = kg + (long)b * 2048 * 512 + h * 128;
  const u16* vbase = vt + (long)(b * 4 + h) * 128 * 2048;        // [dh][kv]
  const unsigned* mbase = mbits + ((long)b * 2048 + qt * 128) * 64;

  // Q fragments in registers: (mi,ks) -> A[m=l16][k=quad*8+j]
  bf16x8 qf[2][4];
#pragma unroll
  for (int mi = 0; mi < 2; mi++)
#pragma unroll
    for (int ks = 0; ks < 4; ks++)
      qf[mi][ks] = *(const bf16x8*)(qbase +
          (long)(qt * 128 + w * 32 + mi * 16 + l16) * 512 + ks * 32 + quad * 8);

  const floatx4 z4 = {0.f, 0.f, 0.f, 0.f};
  floatx4 Oacc[2][8];
#pragma unroll
  for (int mi = 0; mi < 2; mi++)
#pragma unroll
    for (int ni = 0; ni < 8; ni++) Oacc[mi][ni] = z4;
  float mrow[2][4], lrow[2][4];
#pragma unroll
  for (int mi = 0; mi < 2; mi++)
#pragma unroll
    for (int r = 0; r < 4; r++) { mrow[mi][r] = -3.4e38f; lrow[mi][r] = 0.f; }

  const float scale = 0.08838834764831845f;
  const int srow = tid >> 4;            // staging row base
  const int scol = (tid & 15) * 8;      // staging col (elems)

  for (int kt = 0; kt < 16; kt++) {
    __syncthreads();  // prior PV reads of KV/Pl done
    // stage K-tile [kv][dh] + mask words
#pragma unroll
    for (int rr = 0; rr < 128; rr += 16)
      *(int4*)&KV[(rr + srow) * LDP + scol] =
          *(const int4*)(kbase + (long)(kt * 128 + rr + srow) * 512 + scol);
    Ml[tid] = mbase[(tid >> 2) * 64 + kt * 4 + (tid & 3)];
    Ml[tid + 256] = mbase[(64 + (tid >> 2)) * 64 + kt * 4 + (tid & 3)];
    __syncthreads();

    // QK^T
    floatx4 accS[2][8];
#pragma unroll
    for (int mi = 0; mi < 2; mi++)
#pragma unroll
      for (int ni = 0; ni < 8; ni++) accS[mi][ni] = z4;
#pragma unroll
    for (int ks = 0; ks < 4; ks++) {
      bf16x8 bf[8];
#pragma unroll
      for (int ni = 0; ni < 8; ni++)
        bf[ni] = *(const bf16x8*)&KV[(ni * 16 + l16) * LDP + ks * 32 + quad * 8];
#pragma unroll
      for (int mi = 0; mi < 2; mi++)
#pragma unroll
        for (int ni = 0; ni < 8; ni++)
          accS[mi][ni] = __builtin_amdgcn_mfma_f32_16x16x32_bf16(qf[mi][ks], bf[ni], accS[mi][ni], 0, 0, 0);
    }
    __syncthreads();  // KV reads done -> stage V

    // stage V-tile [dh][kv]
#pragma unroll
    for (int rr = 0; rr < 128; rr += 16)
      *(int4*)&KV[(rr + srow) * LDP + scol] =
          *(const int4*)(vbase + (long)(rr + srow) * 2048 + kt * 128 + scol);

    // online softmax (concurrent with V staging; Pl is wave-private)
#pragma unroll
    for (int mi = 0; mi < 2; mi++) {
#pragma unroll
      for (int r = 0; r < 4; r++) {
        const int rowl = w * 32 + mi * 16 + quad * 4 + r;
        float s[8];
        float rmax = -1e30f;
#pragma unroll
        for (int ni = 0; ni < 8; ni++) {
          const unsigned mw = Ml[rowl * 4 + (ni >> 1)];
          const int on = (mw >> ((ni & 1) * 16 + l16)) & 1;
          s[ni] = on ? accS[mi][ni][r] * scale : -1e30f;
          rmax = fmaxf(rmax, s[ni]);
        }
#pragma unroll
        for (int off = 1; off < 16; off <<= 1) rmax = fmaxf(rmax, __shfl_xor(rmax, off, 64));
        const float mnew = fmaxf(mrow[mi][r], rmax);
        const float al = __expf(mrow[mi][r] - mnew);
        float rs = 0.f;
#pragma unroll
        for (int ni = 0; ni < 8; ni++) {
          const float pp = __expf(s[ni] - mnew);
          rs += pp;
          Pl[rowl * LDP + ni * 16 + l16] = f2bf(pp);
        }
#pragma unroll
        for (int off = 1; off < 16; off <<= 1) rs += __shfl_xor(rs, off, 64);
        lrow[mi][r] = lrow[mi][r] * al + rs;
        mrow[mi][r] = mnew;
#pragma unroll
        for (int ni = 0; ni < 8; ni++) Oacc[mi][ni][r] *= al;
      }
    }
    __syncthreads();  // V staged + P written

    // PV
#pragma unroll
    for (int ks = 0; ks < 4; ks++) {
      bf16x8 bv[8];
#pragma unroll
      for (int ni = 0; ni < 8; ni++)
        bv[ni] = *(const bf16x8*)&KV[(ni * 16 + l16) * LDP + ks * 32 + quad * 8];
      bf16x8 pf[2];
#pragma unroll
      for (int mi = 0; mi < 2; mi++)
        pf[mi] = *(const bf16x8*)&Pl[(w * 32 + mi * 16 + l16) * LDP + ks * 32 + quad * 8];
#pragma unroll
      for (int mi = 0; mi < 2; mi++)
#pragma unroll
        for (int ni = 0; ni < 8; ni++)
          Oacc[mi][ni] = __builtin_amdgcn_mfma_f32_16x16x32_bf16(pf[mi], bv[ni], Oacc[mi][ni], 0, 0, 0);
    }
  }

  // epilogue: divide by l, store o[b,q,h,dh] bf16
#pragma unroll
  for (int mi = 0; mi < 2; mi++) {
#pragma unroll
    for (int r = 0; r < 4; r++) {
      const float inv = 1.f / lrow[mi][r];
      const long q = qt * 128 + w * 32 + mi * 16 + quad * 4 + r;
#pragma unroll
      for (int ni = 0; ni < 8; ni++)
        og[((long)b * 2048 + q) * 512 + h * 128 + ni * 16 + l16] = f2bf(Oacc[mi][ni][r] * inv);
    }
  }
}

// ---------------- mask bit-pack: bits[b,q,w] ----------------
__global__ __launch_bounds__(256) void k_maskpack(const int* __restrict__ adjs,
                                                  unsigned* __restrict__ bits) {
  const int wid = blockIdx.x * 4 + (threadIdx.x >> 6);  // global wave id
  const int lane = threadIdx.x & 63;
  const unsigned long long bal = __ballot(adjs[(long)wid * 64 + lane] != 0);
  if (lane == 0) {
    bits[wid * 2] = (unsigned)bal;
    bits[wid * 2 + 1] = (unsigned)(bal >> 32);
  }
}

// ---------------- weight transpose + f32->bf16 ----------------
__global__ __launch_bounds__(256) void tr_w(const float* __restrict__ src, u16* __restrict__ dst,
                                            int ld_src, int ld_dst, long s_z, long d_z) {
  __shared__ u16 tile[32][33];
  src += (long)blockIdx.z * s_z;
  dst += (long)blockIdx.z * d_z;
  const int r0 = blockIdx.x << 5, c0 = blockIdx.y << 5;
  const int tx = threadIdx.x & 31, ty = threadIdx.x >> 5;
#pragma unroll
  for (int i = 0; i < 32; i += 8)
    tile[ty + i][tx] = f2bf(src[(long)(r0 + ty + i) * ld_src + c0 + tx]);
  __syncthreads();
#pragma unroll
  for (int i = 0; i < 32; i += 8)
    dst[(long)(c0 + ty + i) * ld_dst + r0 + tx] = tile[tx][ty + i];
}

// ---------------- bf16 transpose for V ----------------
__global__ __launch_bounds__(256) void tr_bf16(const u16* __restrict__ src, u16* __restrict__ dst,
                                               int ld_src, int ld_dst, int zdiv,
                                               long s_out, long s_in, long d_out, long d_in_) {
  __shared__ u16 tile[32][33];
  const int zz = blockIdx.z, zq = zz / zdiv, zr = zz % zdiv;
  src += (long)zq * s_out + (long)zr * s_in;
  dst += (long)zq * d_out + (long)zr * d_in_;
  const int r0 = blockIdx.x << 5, c0 = blockIdx.y << 5;
  const int tx = threadIdx.x & 31, ty = threadIdx.x >> 5;
#pragma unroll
  for (int i = 0; i < 32; i += 8) tile[ty + i][tx] = src[(long)(r0 + ty + i) * ld_src + c0 + tx];
  __syncthreads();
#pragma unroll
  for (int i = 0; i < 32; i += 8) dst[(long)(c0 + ty + i) * ld_dst + r0 + tx] = tile[tx][ty + i];
}

// ---------------- x = concat(vents, renc_w[rels]) -> f32 + bf16 ----------------
__global__ __launch_bounds__(256) void k_build_x(const float* __restrict__ vents,
                                                 const int* __restrict__ rels,
                                                 const float* __restrict__ renc,
                                                 float* __restrict__ x, u16* __restrict__ xb) {
  const long idx = (long)blockIdx.x * 256 + threadIdx.x;
  const int c = (int)(idx & 511);
  const int row = (int)(idx >> 9);
  const int b = row >> 11, n = row & 2047;
  float val;
  if (n < 1600) val = vents[((long)b * 1600 + n) * 512 + c];
  else val = renc[(long)rels[b * 448 + (n - 1600)] * 512 + c];
  x[idx] = val;
  xb[idx] = f2bf(val);
}

// ---------------- LayerNorm 512: f32 -> f32 + bf16 shadow ----------------
__global__ __launch_bounds__(256) void k_ln(const float* __restrict__ in, float* __restrict__ out,
                                            u16* __restrict__ outb,
                                            const float* __restrict__ g, const float* __restrict__ bb) {
  __shared__ float rs[256], rq[256];
  const int row = blockIdx.x, tid = threadIdx.x;
  const float* p = in + (long)row * 512;
  const float a0 = p[tid], a1 = p[tid + 256];
  rs[tid] = a0 + a1;
  rq[tid] = a0 * a0 + a1 * a1;
  __syncthreads();
  for (int s = 128; s > 0; s >>= 1) {
    if (tid < s) { rs[tid] += rs[tid + s]; rq[tid] += rq[tid + s]; }
    __syncthreads();
  }
  const float mu = rs[0] * (1.f / 512.f);
  const float var = rq[0] * (1.f / 512.f) - mu * mu;
  const float inv = 1.0f / sqrtf(var + 1e-5f);
  const float o0 = (a0 - mu) * inv * g[tid] + bb[tid];
  const float o1 = (a1 - mu) * inv * g[tid + 256] + bb[tid + 256];
  out[(long)row * 512 + tid] = o0;
  out[(long)row * 512 + tid + 256] = o1;
  outb[(long)row * 512 + tid] = f2bf(o0);
  outb[(long)row * 512 + tid + 256] = f2bf(o1);
}

// ---------------- out(f32) = concat(glob, gents, emask) ----------------
__global__ __launch_bounds__(256) void k_out(const float* __restrict__ x, const int* __restrict__ entlen,
                                             float* __restrict__ out, long out_n) {
  const long idx = (long)blockIdx.x * 256 + threadIdx.x;
  if (idx >= out_n) return;
  const long G = 2048, GE = 2048 + 4194304;
  float v;
  if (idx < G) {
    const int b = (int)(idx >> 9), c = (int)(idx & 511);
    int e = entlen[0];
    if (e < 0 || e >= 2048) e = 1600;
    v = x[((long)b * 2048 + e) * 512 + c];
  } else if (idx < GE) {
    v = x[idx - G];
  } else {
    v = 1.0f;
  }
  out[idx] = v;
}

extern "C" void kernel_launch(void* const* d_in, const int* in_sizes, int n_in,
                              void* d_out, int out_size, void* d_ws, size_t ws_size,
                              hipStream_t stream) {
  const int* adjs = (const int*)d_in[0];
  const int* rels = (const int*)d_in[1];
  const float* vents = (const float*)d_in[2];
  const int* entlen = (const int*)d_in[3];
  const float* renc = (const float*)d_in[4];
  const float* Wq = (const float*)d_in[5];
  const float* Wk = (const float*)d_in[6];
  const float* Wv = (const float*)d_in[7];
  const float* Wo = (const float*)d_in[8];
  const float* W1 = (const float*)d_in[9];
  const float* W2 = (const float*)d_in[10];
  const float* bq = (const float*)d_in[11];
  const float* bk = (const float*)d_in[12];
  const float* bv = (const float*)d_in[13];
  const float* bo = (const float*)d_in[14];
  const float* b1 = (const float*)d_in[15];
  const float* b2 = (const float*)d_in[16];
  const float* ln1g = (const float*)d_in[17];
  const float* ln1b = (const float*)d_in[18];
  const float* ln2g = (const float*)d_in[19];
  const float* ln2b = (const float*)d_in[20];
  const float* prelu = (const float*)d_in[21];

  char* base = (char*)d_ws;
  float* x_f   = (float*)(base + 0);           // 16 MB
  float* t_f   = (float*)(base + 16777216);    // 16 MB
  float* tmp_f = (float*)(base + 33554432);    // 16 MB
  u16* wt  = (u16*)(base + 50331648);          // 12 MB
  u16* xb  = (u16*)(base + 62914560);          // 8 MB each
  u16* tb  = (u16*)(base + 71303168);
  u16* qb  = (u16*)(base + 79691776);
  u16* kb  = (u16*)(base + 88080384);
  u16* vb  = (u16*)(base + 96468992);
  u16* Vtb = (u16*)(base + 104857600);
  u16* ob  = (u16*)(base + 113246208);
  u16* hb  = (u16*)(base + 121634816);         // 32 MB
  unsigned* mbits = (unsigned*)(base + 155189248);  // 2 MB

  k_build_x<<<dim3(16384), 256, 0, stream>>>(vents, rels, renc, x_f, xb);
  k_maskpack<<<dim3(65536), 256, 0, stream>>>(adjs, mbits);

  tr_w<<<dim3(16, 16, 2), 256, 0, stream>>>(Wq, wt + 0,       512, 512, 262144L, 3145728L);
  tr_w<<<dim3(16, 16, 2), 256, 0, stream>>>(Wk, wt + 262144,  512, 512, 262144L, 3145728L);
  tr_w<<<dim3(16, 16, 2), 256, 0, stream>>>(Wv, wt + 524288,  512, 512, 262144L, 3145728L);
  tr_w<<<dim3(16, 16, 2), 256, 0, stream>>>(Wo, wt + 786432,  512, 512, 262144L, 3145728L);
  tr_w<<<dim3(16, 64, 2), 256, 0, stream>>>(W1, wt + 1048576, 2048, 512, 1048576L, 3145728L);
  tr_w<<<dim3(64, 16, 2), 256, 0, stream>>>(W2, wt + 2097152, 512, 2048, 1048576L, 3145728L);

  for (int j = 0; j < 2; j++) {
    const u16* wqt = wt + (long)j * 3145728;
    const u16* wkt = wqt + 262144;
    const u16* wvt = wqt + 524288;
    const u16* wot = wqt + 786432;
    const u16* w1t = wqt + 1048576;
    const u16* w2t = wqt + 2097152;

    gemm_tn<1, 0><<<dim3(64, 4), 256, 0, stream>>>(xb, wqt, qb, bq + j * 512, nullptr, nullptr, 512, 512, 512, 512);
    gemm_tn<1, 0><<<dim3(64, 4), 256, 0, stream>>>(xb, wkt, kb, bk + j * 512, nullptr, nullptr, 512, 512, 512, 512);
    gemm_tn<1, 0><<<dim3(64, 4), 256, 0, stream>>>(xb, wvt, vb, bv + j * 512, nullptr, nullptr, 512, 512, 512, 512);

    // Vtb[b,h,dh,kv] = vb[b,kv,h,dh]
    tr_bf16<<<dim3(64, 4, 16), 256, 0, stream>>>(vb, Vtb, 512, 2048, 4,
        1048576L, 128L, 1048576L, 262144L);

    // fused attention -> ob
    k_attn<<<dim3(16, 16), 256, 0, stream>>>(qb, kb, Vtb, mbits, ob);

    // attn_out(f32) = ob @ Wo + bo -> tmp
    gemm_tn<1, 1><<<dim3(64, 4), 256, 0, stream>>>(ob, wot, tmp_f, bo + j * 512, nullptr, nullptr, 512, 512, 512, 512);
    // t = LN1(tmp)
    k_ln<<<dim3(8192), 256, 0, stream>>>(tmp_f, t_f, tb, ln1g + j * 512, ln1b + j * 512);
    // hb(bf16) = PReLU(t @ W1 + b1)
    gemm_tn<2, 0><<<dim3(64, 16), 256, 0, stream>>>(tb, w1t, hb, b1 + j * 2048, prelu + j * 2048, nullptr, 512, 512, 512, 2048);
    // tmp(f32) = hb @ W2 + b2 + t_f
    gemm_tn<3, 1><<<dim3(64, 4), 256, 0, stream>>>(hb, w2t, tmp_f, b2 + j * 512, nullptr, t_f, 2048, 2048, 2048, 512);
    // x = LN2(tmp)
    k_ln<<<dim3(8192), 256, 0, stream>>>(tmp_f, x_f, xb, ln2g + j * 512, ln2b + j * 512);
  }

  const long out_n = (long)out_size;
  k_out<<<dim3((unsigned)((out_n + 255) / 256)), 256, 0, stream>>>(x_f, entlen, (float*)d_out, out_n);
}